// Round 5
// baseline (745.312 us; speedup 1.0000x reference)
//
#include <hip/hip_runtime.h>
#include <cstdint>
#include <cstddef>

#define IN_DIM  256
#define H_DIM   256
#define OUT_DIM 128
#define MEDGES  20000

typedef unsigned short u16;
typedef unsigned int   u32;
typedef short bf16x8 __attribute__((ext_vector_type(8)));
typedef float f32x4  __attribute__((ext_vector_type(4)));

__device__ __forceinline__ float bf2f(u16 u) {
    u32 x = ((u32)u) << 16;
    float f;
    __builtin_memcpy(&f, &x, 4);
    return f;
}
// round-to-nearest-even float -> bf16 (finite inputs)
__device__ __forceinline__ u16 f2bf(float f) {
    u32 x;
    __builtin_memcpy(&x, &f, 4);
    u32 r = x + 0x7fffu + ((x >> 16) & 1u);
    return (u16)(r >> 16);
}

// ======================= fused convert fp32 -> bf16 (X, W1, W2) =======================
__global__ void cvt_all(const float4* __restrict__ X,  ushort4* __restrict__ Xb,  int nX,
                        const float4* __restrict__ W1, ushort4* __restrict__ W1b, int nW1,
                        const float4* __restrict__ W2, ushort4* __restrict__ W2b, int nW2)
{
    int i = blockIdx.x * blockDim.x + threadIdx.x;
    const float4* s; ushort4* d; int k;
    if (i < nX)                  { s = X;  d = Xb;  k = i; }
    else if (i < nX + nW1)       { s = W1; d = W1b; k = i - nX; }
    else if (i < nX + nW1 + nW2) { s = W2; d = W2b; k = i - nX - nW1; }
    else return;
    float4 v = s[k];
    ushort4 o;
    o.x = f2bf(v.x); o.y = f2bf(v.y); o.z = f2bf(v.z); o.w = f2bf(v.w);
    d[k] = o;
}

// ======================= CSR build =======================

__global__ void hist_rank_kernel(const int* __restrict__ e_idx, const int* __restrict__ v_idx,
                                 int* __restrict__ cnt_e, int* __restrict__ cnt_v,
                                 int* __restrict__ rank_e, int* __restrict__ rank_v, int nnz)
{
    int i = blockIdx.x * blockDim.x + threadIdx.x;
    if (i < nnz) {
        rank_e[i] = atomicAdd(&cnt_e[e_idx[i]], 1);
        rank_v[i] = atomicAdd(&cnt_v[v_idx[i]], 1);
    }
}

// Single-block fused exclusive scan: off[0..n-1] = exclusive prefix of cnt, off[n] = nnz.
__global__ __launch_bounds__(1024) void scan_single(const int* __restrict__ cnt,
                                                    int* __restrict__ off, int n, int nnz)
{
    __shared__ int part[1024];
    int t = threadIdx.x;
    int chunk = (n + 1023) >> 10;
    int s = t * chunk;
    int e = min(s + chunk, n);
    int sum = 0;
    for (int i = s; i < e; ++i) sum += cnt[i];
    part[t] = sum;
    __syncthreads();
    for (int o = 1; o < 1024; o <<= 1) {
        int v = (t >= o) ? part[t - o] : 0;
        __syncthreads();
        part[t] += v;
        __syncthreads();
    }
    int run = part[t] - sum;   // exclusive base for this thread's chunk
    for (int i = s; i < e; ++i) { off[i] = run; run += cnt[i]; }
    if (t == 0) off[n] = nnz;
}

__global__ void scatter_kernel(const int* __restrict__ e_idx, const int* __restrict__ v_idx,
                               const int* __restrict__ e_off, const int* __restrict__ v_off,
                               const int* __restrict__ rank_e, const int* __restrict__ rank_v,
                               int* __restrict__ e_list, int* __restrict__ v_list, int nnz)
{
    int i = blockIdx.x * blockDim.x + threadIdx.x;
    if (i < nnz) {
        int e = e_idx[i], v = v_idx[i];
        e_list[e_off[e] + rank_e[i]] = v;
        v_list[v_off[v] + rank_v[i]] = e;
    }
}

// ======================= segment mean: wave-per-segment =======================
// D = 256: each of 64 lanes owns 4 contiguous bf16 (ushort4, 8 B/lane -> one 512 B row read
// per wave instruction). Unroll-4 rows for memory-level parallelism. Indices scalarized.
__global__ void seg_mean_w4(const ushort4* __restrict__ src, ushort4* __restrict__ dst,
                            const int* __restrict__ off, const int* __restrict__ lst,
                            int nseg, int do_relu)
{
    int wid  = (blockIdx.x * blockDim.x + threadIdx.x) >> 6;
    int lane = threadIdx.x & 63;
    if (wid >= nseg) return;
    int beg = __builtin_amdgcn_readfirstlane(off[wid]);
    int end = __builtin_amdgcn_readfirstlane(off[wid + 1]);
    float ax = 0.f, ay = 0.f, az = 0.f, aw = 0.f;
    int j = beg;
    for (; j + 3 < end; j += 4) {
        int i0 = lst[j], i1 = lst[j + 1], i2 = lst[j + 2], i3 = lst[j + 3];
        ushort4 a = src[(size_t)i0 * 64 + lane];
        ushort4 b = src[(size_t)i1 * 64 + lane];
        ushort4 c = src[(size_t)i2 * 64 + lane];
        ushort4 d = src[(size_t)i3 * 64 + lane];
        ax += bf2f(a.x) + bf2f(b.x) + bf2f(c.x) + bf2f(d.x);
        ay += bf2f(a.y) + bf2f(b.y) + bf2f(c.y) + bf2f(d.y);
        az += bf2f(a.z) + bf2f(b.z) + bf2f(c.z) + bf2f(d.z);
        aw += bf2f(a.w) + bf2f(b.w) + bf2f(c.w) + bf2f(d.w);
    }
    for (; j < end; ++j) {
        ushort4 a = src[(size_t)lst[j] * 64 + lane];
        ax += bf2f(a.x); ay += bf2f(a.y); az += bf2f(a.z); aw += bf2f(a.w);
    }
    int cnt = end - beg;
    float inv = (cnt > 0) ? 1.f / (float)cnt : 0.f;
    ax *= inv; ay *= inv; az *= inv; aw *= inv;
    if (do_relu) {
        ax = fmaxf(ax, 0.f); ay = fmaxf(ay, 0.f);
        az = fmaxf(az, 0.f); aw = fmaxf(aw, 0.f);
    }
    ushort4 o;
    o.x = f2bf(ax); o.y = f2bf(ay); o.z = f2bf(az); o.w = f2bf(aw);
    dst[(size_t)wid * 64 + lane] = o;
}

// D = 128: ushort2 per lane (4 B/lane -> 256 B row reads).
__global__ void seg_mean_w2(const ushort2* __restrict__ src, ushort2* __restrict__ dst,
                            const int* __restrict__ off, const int* __restrict__ lst,
                            int nseg, int do_relu)
{
    int wid  = (blockIdx.x * blockDim.x + threadIdx.x) >> 6;
    int lane = threadIdx.x & 63;
    if (wid >= nseg) return;
    int beg = __builtin_amdgcn_readfirstlane(off[wid]);
    int end = __builtin_amdgcn_readfirstlane(off[wid + 1]);
    float ax = 0.f, ay = 0.f;
    int j = beg;
    for (; j + 3 < end; j += 4) {
        int i0 = lst[j], i1 = lst[j + 1], i2 = lst[j + 2], i3 = lst[j + 3];
        ushort2 a = src[(size_t)i0 * 64 + lane];
        ushort2 b = src[(size_t)i1 * 64 + lane];
        ushort2 c = src[(size_t)i2 * 64 + lane];
        ushort2 d = src[(size_t)i3 * 64 + lane];
        ax += bf2f(a.x) + bf2f(b.x) + bf2f(c.x) + bf2f(d.x);
        ay += bf2f(a.y) + bf2f(b.y) + bf2f(c.y) + bf2f(d.y);
    }
    for (; j < end; ++j) {
        ushort2 a = src[(size_t)lst[j] * 64 + lane];
        ax += bf2f(a.x); ay += bf2f(a.y);
    }
    int cnt = end - beg;
    float inv = (cnt > 0) ? 1.f / (float)cnt : 0.f;
    ax *= inv; ay *= inv;
    if (do_relu) { ax = fmaxf(ax, 0.f); ay = fmaxf(ay, 0.f); }
    ushort2 o;
    o.x = f2bf(ax); o.y = f2bf(ay);
    dst[(size_t)wid * 64 + lane] = o;
}

// ======================= MFMA bf16 GEMM + bias, bf16 out =======================
// C[R x Cc](bf16) = A[R x K](bf16) @ W[K x Cc](bf16) + bias(f32).
// 64x64 tile, BK=32, 256 threads = 4 waves; wave w computes rows [16w,16w+16).
#define GSTRIDE 40   // LDS row stride in elements (80 B)
__global__ __launch_bounds__(256) void gemm_mfma_bf16(const u16* __restrict__ A,
                                                      const u16* __restrict__ W,
                                                      const float* __restrict__ bias,
                                                      u16* __restrict__ C,
                                                      int R, int K, int Cc)
{
    __shared__ __align__(16) u16 As[64 * GSTRIDE];   // [row][k] 64x32
    __shared__ __align__(16) u16 Bs[64 * GSTRIDE];   // [n][k]   64x32 (transposed)

    int tid  = threadIdx.x;
    int wave = tid >> 6;
    int lane = tid & 63;
    int quad = lane >> 4;
    int l16  = lane & 15;

    int row0 = blockIdx.y * 64;
    int col0 = blockIdx.x * 64;

    f32x4 acc[4] = {};

    int ar   = tid >> 2;   // 0..63 A row
    int aseg = tid & 3;    // k-offset 8*aseg
    int bk   = tid >> 3;   // 0..31 W k-row
    int bn   = tid & 7;    // n-offset 8*bn

    for (int k0 = 0; k0 < K; k0 += 32) {
        bf16x8 av = {};
        int gr = row0 + ar;
        if (gr < R) av = *(const bf16x8*)&A[(size_t)gr * K + k0 + 8 * aseg];
        *(bf16x8*)&As[ar * GSTRIDE + 8 * aseg] = av;
        bf16x8 wv = *(const bf16x8*)&W[(size_t)(k0 + bk) * Cc + col0 + 8 * bn];
#pragma unroll
        for (int j = 0; j < 8; ++j)
            Bs[(8 * bn + j) * GSTRIDE + bk] = ((const u16*)&wv)[j];
        __syncthreads();

        bf16x8 af = *(const bf16x8*)&As[(16 * wave + l16) * GSTRIDE + 8 * quad];
#pragma unroll
        for (int nt = 0; nt < 4; ++nt) {
            bf16x8 bfv = *(const bf16x8*)&Bs[(16 * nt + l16) * GSTRIDE + 8 * quad];
            acc[nt] = __builtin_amdgcn_mfma_f32_16x16x32_bf16(af, bfv, acc[nt], 0, 0, 0);
        }
        __syncthreads();
    }

#pragma unroll
    for (int nt = 0; nt < 4; ++nt) {
        int col = col0 + 16 * nt + l16;
        float bv = bias[col];
#pragma unroll
        for (int r = 0; r < 4; ++r) {
            int grow = row0 + 16 * wave + 4 * quad + r;
            if (grow < R) C[(size_t)grow * Cc + col] = f2bf(acc[nt][r] + bv);
        }
    }
}

// ======================= link head =======================
__global__ void link_head(const ushort2* __restrict__ h2, const int* __restrict__ link,
                          const float* __restrict__ fc_w, const float* __restrict__ fc_b,
                          float* __restrict__ out, int L)
{
    int gtid = blockIdx.x * blockDim.x + threadIdx.x;
    int wid  = gtid >> 6;
    int lane = threadIdx.x & 63;
    if (wid >= L) return;
    const int Dh = OUT_DIM / 2;   // 64 pairs
    int a = link[2 * wid + 0];
    int b = link[2 * wid + 1];
    ushort2 ra = h2[(size_t)a * Dh + lane];
    ushort2 rb = h2[(size_t)b * Dh + lane];
    float2 w = *(const float2*)&fc_w[2 * lane];
    float acc = 0.5f * ((bf2f(ra.x) + bf2f(rb.x)) * w.x + (bf2f(ra.y) + bf2f(rb.y)) * w.y);
#pragma unroll
    for (int off = 32; off; off >>= 1) acc += __shfl_xor(acc, off, 64);
    if (lane == 0) out[wid] = 1.f / (1.f + expf(-(acc + fc_b[0])));
}

// ======================= launch =======================

static inline size_t align_up(size_t x, size_t a) { return (x + a - 1) & ~(a - 1); }

extern "C" void kernel_launch(void* const* d_in, const int* in_sizes, int n_in,
                              void* d_out, int out_size, void* d_ws, size_t ws_size,
                              hipStream_t stream)
{
    const float* X   = (const float*)d_in[0];
    const float* W1  = (const float*)d_in[1];
    const float* b1  = (const float*)d_in[2];
    const float* W2  = (const float*)d_in[3];
    const float* b2  = (const float*)d_in[4];
    const float* fcw = (const float*)d_in[5];
    const float* fcb = (const float*)d_in[6];
    const int* v_idx = (const int*)d_in[7];
    const int* e_idx = (const int*)d_in[8];
    const int* link  = (const int*)d_in[9];
    float* out = (float*)d_out;

    const int NNZ = in_sizes[7];
    const int N   = in_sizes[0] / IN_DIM;
    const int L   = in_sizes[9] / 2;
    const int M   = MEDGES;
    const int Mpad = align_up(M, 64);   // cnt_e rounded so cnt_v stays 256B-aligned

    char* p = (char*)d_ws;
    auto carve = [&](size_t bytes) -> void* {
        void* r = (void*)p;
        p += align_up(bytes, 256);
        return r;
    };
    u16*  Xb    = (u16*)carve((size_t)N * IN_DIM * 2);   // X bf16; reused as h2b (N x 128)
    u16*  h1b   = (u16*)carve((size_t)N * H_DIM * 2);    // h1 bf16
    u16*  Aggb  = (u16*)carve((size_t)M * H_DIM * 2);    // Xe/He bf16 (GEMM A)
    u16*  Yb    = (u16*)carve((size_t)M * H_DIM * 2);    // Y1b / Y2b
    u16*  W1b   = (u16*)carve((size_t)IN_DIM * H_DIM * 2);
    u16*  W2b   = (u16*)carve((size_t)H_DIM * OUT_DIM * 2);
    int*  e_off = (int*)carve((size_t)(M + 1) * 4);
    int*  v_off = (int*)carve((size_t)(N + 1) * 4);
    int*  cnt_e = (int*)carve((size_t)(Mpad + N) * 4);   // cnt_e ++ cnt_v, one memset
    int*  cnt_v = cnt_e + Mpad;
    int*  rank_e= (int*)carve((size_t)NNZ * 4);
    int*  rank_v= (int*)carve((size_t)NNZ * 4);
    int*  e_lst = (int*)carve((size_t)NNZ * 4);
    int*  v_lst = (int*)carve((size_t)NNZ * 4);

    (void)hipMemsetAsync(cnt_e, 0, (size_t)(Mpad + N) * 4, stream);

    const int tb = 256;

    // fused converts (overlap with CSR build on other CUs)
    int nX  = N * IN_DIM / 4;
    int nW1 = IN_DIM * H_DIM / 4;
    int nW2 = H_DIM * OUT_DIM / 4;
    cvt_all<<<(nX + nW1 + nW2 + tb - 1) / tb, tb, 0, stream>>>(
        (const float4*)X, (ushort4*)Xb, nX,
        (const float4*)W1, (ushort4*)W1b, nW1,
        (const float4*)W2, (ushort4*)W2b, nW2);

    hist_rank_kernel<<<(NNZ + tb - 1) / tb, tb, 0, stream>>>(e_idx, v_idx, cnt_e, cnt_v,
                                                             rank_e, rank_v, NNZ);

    scan_single<<<1, 1024, 0, stream>>>(cnt_e, e_off, M, NNZ);
    scan_single<<<1, 1024, 0, stream>>>(cnt_v, v_off, N, NNZ);

    scatter_kernel<<<(NNZ + tb - 1) / tb, tb, 0, stream>>>(e_idx, v_idx, e_off, v_off,
                                                           rank_e, rank_v, e_lst, v_lst, NNZ);

    // ---- conv1 ----
    // Aggb = bf16(mean_v2e(Xb))        [M x 256]
    seg_mean_w4<<<((size_t)M * 64 + tb - 1) / tb, tb, 0, stream>>>(
        (const ushort4*)Xb, (ushort4*)Aggb, e_off, e_lst, M, 0);
    // Y1b = bf16(Aggb @ W1b + b1)      [M x 256]  (MFMA)
    gemm_mfma_bf16<<<dim3(H_DIM / 64, (M + 63) / 64), 256, 0, stream>>>(Aggb, W1b, b1, Yb, M, IN_DIM, H_DIM);
    // h1b = bf16(relu(mean_e2v(Y1b)))  [N x 256]
    seg_mean_w4<<<((size_t)N * 64 + tb - 1) / tb, tb, 0, stream>>>(
        (const ushort4*)Yb, (ushort4*)h1b, v_off, v_lst, N, 1);

    // ---- conv2 ----
    // Aggb = bf16(mean_v2e(h1b))       [M x 256]
    seg_mean_w4<<<((size_t)M * 64 + tb - 1) / tb, tb, 0, stream>>>(
        (const ushort4*)h1b, (ushort4*)Aggb, e_off, e_lst, M, 0);
    // Y2b = bf16(Aggb @ W2b + b2)      [M x 128]  (MFMA)
    gemm_mfma_bf16<<<dim3(OUT_DIM / 64, (M + 63) / 64), 256, 0, stream>>>(Aggb, W2b, b2, Yb, M, H_DIM, OUT_DIM);
    // h2b = bf16(relu(mean_e2v(Y2b)))  [N x 128]  (reuses Xb)
    seg_mean_w2<<<((size_t)N * 64 + tb - 1) / tb, tb, 0, stream>>>(
        (const ushort2*)Yb, (ushort2*)Xb, v_off, v_lst, N, 1);

    // ---- link head ----
    link_head<<<((size_t)L * 64 + tb - 1) / tb, tb, 0, stream>>>(
        (const ushort2*)Xb, link, fcw, fcb, out, L);
}

// Round 6
// 585.681 us; speedup vs baseline: 1.2726x; 1.2726x over previous
//
#include <hip/hip_runtime.h>
#include <cstdint>
#include <cstddef>

#define IN_DIM  256
#define H_DIM   256
#define OUT_DIM 128
#define MEDGES  20000

typedef unsigned short u16;
typedef unsigned int   u32;
typedef short bf16x8 __attribute__((ext_vector_type(8)));
typedef float f32x4  __attribute__((ext_vector_type(4)));

__device__ __forceinline__ float bf2f(u16 u) {
    u32 x = ((u32)u) << 16;
    float f;
    __builtin_memcpy(&f, &x, 4);
    return f;
}
// round-to-nearest-even float -> bf16 (finite inputs)
__device__ __forceinline__ u16 f2bf(float f) {
    u32 x;
    __builtin_memcpy(&x, &f, 4);
    u32 r = x + 0x7fffu + ((x >> 16) & 1u);
    return (u16)(r >> 16);
}

// ======================= fused convert fp32 -> bf16 (X, W1, W2) =======================
__global__ void cvt_all(const float4* __restrict__ X,  ushort4* __restrict__ Xb,  int nX,
                        const float4* __restrict__ W1, ushort4* __restrict__ W1b, int nW1,
                        const float4* __restrict__ W2, ushort4* __restrict__ W2b, int nW2)
{
    int i = blockIdx.x * blockDim.x + threadIdx.x;
    const float4* s; ushort4* d; int k;
    if (i < nX)                  { s = X;  d = Xb;  k = i; }
    else if (i < nX + nW1)       { s = W1; d = W1b; k = i - nX; }
    else if (i < nX + nW1 + nW2) { s = W2; d = W2b; k = i - nX - nW1; }
    else return;
    float4 v = s[k];
    ushort4 o;
    o.x = f2bf(v.x); o.y = f2bf(v.y); o.z = f2bf(v.z); o.w = f2bf(v.w);
    d[k] = o;
}

// ======================= CSR build =======================

__global__ void hist_rank_kernel(const int* __restrict__ e_idx, const int* __restrict__ v_idx,
                                 int* __restrict__ cnt_e, int* __restrict__ cnt_v,
                                 int* __restrict__ rank_e, int* __restrict__ rank_v, int nnz)
{
    int i = blockIdx.x * blockDim.x + threadIdx.x;
    if (i < nnz) {
        rank_e[i] = atomicAdd(&cnt_e[e_idx[i]], 1);
        rank_v[i] = atomicAdd(&cnt_v[v_idx[i]], 1);
    }
}

#define SCAN_B 1024
__global__ void scan_block_kernel(const int* __restrict__ in, int* __restrict__ out,
                                  int* __restrict__ bsums, int n)
{
    __shared__ int s[SCAN_B];
    int gid = blockIdx.x * SCAN_B + threadIdx.x;
    int x = (gid < n) ? in[gid] : 0;
    s[threadIdx.x] = x;
    __syncthreads();
    for (int off = 1; off < SCAN_B; off <<= 1) {
        int v = (threadIdx.x >= off) ? s[threadIdx.x - off] : 0;
        __syncthreads();
        s[threadIdx.x] += v;
        __syncthreads();
    }
    if (gid < n) out[gid] = s[threadIdx.x] - x;   // exclusive
    if (threadIdx.x == SCAN_B - 1) bsums[blockIdx.x] = s[SCAN_B - 1];
}

__global__ void scan_top_kernel(int* bsums, int nb)
{
    if (threadIdx.x == 0 && blockIdx.x == 0) {
        int run = 0;
        for (int i = 0; i < nb; ++i) { int v = bsums[i]; bsums[i] = run; run += v; }
    }
}

__global__ void scan_add_kernel(int* __restrict__ out, const int* __restrict__ bsums, int n)
{
    int gid = blockIdx.x * SCAN_B + threadIdx.x;
    if (gid < n) out[gid] += bsums[blockIdx.x];
}

__global__ void set_tail_kernel(int* e_off, int* v_off, int nnz, int m, int n)
{
    if (threadIdx.x == 0 && blockIdx.x == 0) { e_off[m] = nnz; v_off[n] = nnz; }
}

__global__ void scatter_kernel(const int* __restrict__ e_idx, const int* __restrict__ v_idx,
                               const int* __restrict__ e_off, const int* __restrict__ v_off,
                               const int* __restrict__ rank_e, const int* __restrict__ rank_v,
                               int* __restrict__ e_list, int* __restrict__ v_list, int nnz)
{
    int i = blockIdx.x * blockDim.x + threadIdx.x;
    if (i < nnz) {
        int e = e_idx[i], v = v_idx[i];
        e_list[e_off[e] + rank_e[i]] = v;
        v_list[v_off[v] + rank_v[i]] = e;
    }
}

// ======================= segment mean: wave-per-segment =======================
// D = 256: each of 64 lanes owns 4 contiguous bf16 (ushort4, 8 B/lane). Unroll-4 rows
// for memory-level parallelism. Segment bounds scalarized via readfirstlane.
__global__ void seg_mean_w4(const ushort4* __restrict__ src, ushort4* __restrict__ dst,
                            const int* __restrict__ off, const int* __restrict__ lst,
                            int nseg, int do_relu)
{
    int wid  = (blockIdx.x * blockDim.x + threadIdx.x) >> 6;
    int lane = threadIdx.x & 63;
    if (wid >= nseg) return;
    int beg = __builtin_amdgcn_readfirstlane(off[wid]);
    int end = __builtin_amdgcn_readfirstlane(off[wid + 1]);
    float ax = 0.f, ay = 0.f, az = 0.f, aw = 0.f;
    int j = beg;
    for (; j + 3 < end; j += 4) {
        int i0 = lst[j], i1 = lst[j + 1], i2 = lst[j + 2], i3 = lst[j + 3];
        ushort4 a = src[(size_t)i0 * 64 + lane];
        ushort4 b = src[(size_t)i1 * 64 + lane];
        ushort4 c = src[(size_t)i2 * 64 + lane];
        ushort4 d = src[(size_t)i3 * 64 + lane];
        ax += bf2f(a.x) + bf2f(b.x) + bf2f(c.x) + bf2f(d.x);
        ay += bf2f(a.y) + bf2f(b.y) + bf2f(c.y) + bf2f(d.y);
        az += bf2f(a.z) + bf2f(b.z) + bf2f(c.z) + bf2f(d.z);
        aw += bf2f(a.w) + bf2f(b.w) + bf2f(c.w) + bf2f(d.w);
    }
    for (; j < end; ++j) {
        ushort4 a = src[(size_t)lst[j] * 64 + lane];
        ax += bf2f(a.x); ay += bf2f(a.y); az += bf2f(a.z); aw += bf2f(a.w);
    }
    int cnt = end - beg;
    float inv = (cnt > 0) ? 1.f / (float)cnt : 0.f;
    ax *= inv; ay *= inv; az *= inv; aw *= inv;
    if (do_relu) {
        ax = fmaxf(ax, 0.f); ay = fmaxf(ay, 0.f);
        az = fmaxf(az, 0.f); aw = fmaxf(aw, 0.f);
    }
    ushort4 o;
    o.x = f2bf(ax); o.y = f2bf(ay); o.z = f2bf(az); o.w = f2bf(aw);
    dst[(size_t)wid * 64 + lane] = o;
}

// D = 128: ushort2 per lane.
__global__ void seg_mean_w2(const ushort2* __restrict__ src, ushort2* __restrict__ dst,
                            const int* __restrict__ off, const int* __restrict__ lst,
                            int nseg, int do_relu)
{
    int wid  = (blockIdx.x * blockDim.x + threadIdx.x) >> 6;
    int lane = threadIdx.x & 63;
    if (wid >= nseg) return;
    int beg = __builtin_amdgcn_readfirstlane(off[wid]);
    int end = __builtin_amdgcn_readfirstlane(off[wid + 1]);
    float ax = 0.f, ay = 0.f;
    int j = beg;
    for (; j + 3 < end; j += 4) {
        int i0 = lst[j], i1 = lst[j + 1], i2 = lst[j + 2], i3 = lst[j + 3];
        ushort2 a = src[(size_t)i0 * 64 + lane];
        ushort2 b = src[(size_t)i1 * 64 + lane];
        ushort2 c = src[(size_t)i2 * 64 + lane];
        ushort2 d = src[(size_t)i3 * 64 + lane];
        ax += bf2f(a.x) + bf2f(b.x) + bf2f(c.x) + bf2f(d.x);
        ay += bf2f(a.y) + bf2f(b.y) + bf2f(c.y) + bf2f(d.y);
    }
    for (; j < end; ++j) {
        ushort2 a = src[(size_t)lst[j] * 64 + lane];
        ax += bf2f(a.x); ay += bf2f(a.y);
    }
    int cnt = end - beg;
    float inv = (cnt > 0) ? 1.f / (float)cnt : 0.f;
    ax *= inv; ay *= inv;
    if (do_relu) { ax = fmaxf(ax, 0.f); ay = fmaxf(ay, 0.f); }
    ushort2 o;
    o.x = f2bf(ax); o.y = f2bf(ay);
    dst[(size_t)wid * 64 + lane] = o;
}

// ======================= MFMA bf16 GEMM + bias, bf16 out =======================
#define GSTRIDE 40   // LDS row stride in elements (80 B)
__global__ __launch_bounds__(256) void gemm_mfma_bf16(const u16* __restrict__ A,
                                                      const u16* __restrict__ W,
                                                      const float* __restrict__ bias,
                                                      u16* __restrict__ C,
                                                      int R, int K, int Cc)
{
    __shared__ __align__(16) u16 As[64 * GSTRIDE];   // [row][k] 64x32
    __shared__ __align__(16) u16 Bs[64 * GSTRIDE];   // [n][k]   64x32 (transposed)

    int tid  = threadIdx.x;
    int wave = tid >> 6;
    int lane = tid & 63;
    int quad = lane >> 4;
    int l16  = lane & 15;

    int row0 = blockIdx.y * 64;
    int col0 = blockIdx.x * 64;

    f32x4 acc[4] = {};

    int ar   = tid >> 2;   // 0..63 A row
    int aseg = tid & 3;    // k-offset 8*aseg
    int bk   = tid >> 3;   // 0..31 W k-row
    int bn   = tid & 7;    // n-offset 8*bn

    for (int k0 = 0; k0 < K; k0 += 32) {
        bf16x8 av = {};
        int gr = row0 + ar;
        if (gr < R) av = *(const bf16x8*)&A[(size_t)gr * K + k0 + 8 * aseg];
        *(bf16x8*)&As[ar * GSTRIDE + 8 * aseg] = av;
        bf16x8 wv = *(const bf16x8*)&W[(size_t)(k0 + bk) * Cc + col0 + 8 * bn];
#pragma unroll
        for (int j = 0; j < 8; ++j)
            Bs[(8 * bn + j) * GSTRIDE + bk] = ((const u16*)&wv)[j];
        __syncthreads();

        bf16x8 af = *(const bf16x8*)&As[(16 * wave + l16) * GSTRIDE + 8 * quad];
#pragma unroll
        for (int nt = 0; nt < 4; ++nt) {
            bf16x8 bfv = *(const bf16x8*)&Bs[(16 * nt + l16) * GSTRIDE + 8 * quad];
            acc[nt] = __builtin_amdgcn_mfma_f32_16x16x32_bf16(af, bfv, acc[nt], 0, 0, 0);
        }
        __syncthreads();
    }

#pragma unroll
    for (int nt = 0; nt < 4; ++nt) {
        int col = col0 + 16 * nt + l16;
        float bv = bias[col];
#pragma unroll
        for (int r = 0; r < 4; ++r) {
            int grow = row0 + 16 * wave + 4 * quad + r;
            if (grow < R) C[(size_t)grow * Cc + col] = f2bf(acc[nt][r] + bv);
        }
    }
}

// ======================= link head =======================
__global__ void link_head(const ushort2* __restrict__ h2, const int* __restrict__ link,
                          const float* __restrict__ fc_w, const float* __restrict__ fc_b,
                          float* __restrict__ out, int L)
{
    int gtid = blockIdx.x * blockDim.x + threadIdx.x;
    int wid  = gtid >> 6;
    int lane = threadIdx.x & 63;
    if (wid >= L) return;
    const int Dh = OUT_DIM / 2;   // 64 pairs
    int a = link[2 * wid + 0];
    int b = link[2 * wid + 1];
    ushort2 ra = h2[(size_t)a * Dh + lane];
    ushort2 rb = h2[(size_t)b * Dh + lane];
    float2 w = *(const float2*)&fc_w[2 * lane];
    float acc = 0.5f * ((bf2f(ra.x) + bf2f(rb.x)) * w.x + (bf2f(ra.y) + bf2f(rb.y)) * w.y);
#pragma unroll
    for (int off = 32; off; off >>= 1) acc += __shfl_xor(acc, off, 64);
    if (lane == 0) out[wid] = 1.f / (1.f + expf(-(acc + fc_b[0])));
}

// ======================= launch =======================

static inline size_t align_up(size_t x, size_t a) { return (x + a - 1) & ~(a - 1); }

extern "C" void kernel_launch(void* const* d_in, const int* in_sizes, int n_in,
                              void* d_out, int out_size, void* d_ws, size_t ws_size,
                              hipStream_t stream)
{
    const float* X   = (const float*)d_in[0];
    const float* W1  = (const float*)d_in[1];
    const float* b1  = (const float*)d_in[2];
    const float* W2  = (const float*)d_in[3];
    const float* b2  = (const float*)d_in[4];
    const float* fcw = (const float*)d_in[5];
    const float* fcb = (const float*)d_in[6];
    const int* v_idx = (const int*)d_in[7];
    const int* e_idx = (const int*)d_in[8];
    const int* link  = (const int*)d_in[9];
    float* out = (float*)d_out;

    const int NNZ = in_sizes[7];
    const int N   = in_sizes[0] / IN_DIM;
    const int L   = in_sizes[9] / 2;
    const int M   = MEDGES;
    const int Mpad = align_up(M, 64);

    char* p = (char*)d_ws;
    auto carve = [&](size_t bytes) -> void* {
        void* r = (void*)p;
        p += align_up(bytes, 256);
        return r;
    };
    u16*  Xb    = (u16*)carve((size_t)N * IN_DIM * 2);   // X bf16; reused as h2b (N x 128)
    u16*  h1b   = (u16*)carve((size_t)N * H_DIM * 2);    // h1 bf16
    u16*  Aggb  = (u16*)carve((size_t)M * H_DIM * 2);    // Xe/He bf16 (GEMM A)
    u16*  Yb    = (u16*)carve((size_t)M * H_DIM * 2);    // Y1b / Y2b
    u16*  W1b   = (u16*)carve((size_t)IN_DIM * H_DIM * 2);
    u16*  W2b   = (u16*)carve((size_t)H_DIM * OUT_DIM * 2);
    int*  e_off = (int*)carve((size_t)(M + 1) * 4);
    int*  v_off = (int*)carve((size_t)(N + 1) * 4);
    int*  cnt_e = (int*)carve((size_t)(Mpad + N) * 4);   // cnt_e ++ cnt_v, one memset
    int*  cnt_v = cnt_e + Mpad;
    int*  rank_e= (int*)carve((size_t)NNZ * 4);
    int*  rank_v= (int*)carve((size_t)NNZ * 4);
    int*  e_lst = (int*)carve((size_t)NNZ * 4);
    int*  v_lst = (int*)carve((size_t)NNZ * 4);
    int*  bsums = (int*)carve(4096);

    (void)hipMemsetAsync(cnt_e, 0, (size_t)(Mpad + N) * 4, stream);

    const int tb = 256;

    // fused converts (overlap with CSR build on other CUs)
    int nX  = N * IN_DIM / 4;
    int nW1 = IN_DIM * H_DIM / 4;
    int nW2 = H_DIM * OUT_DIM / 4;
    cvt_all<<<(nX + nW1 + nW2 + tb - 1) / tb, tb, 0, stream>>>(
        (const float4*)X, (ushort4*)Xb, nX,
        (const float4*)W1, (ushort4*)W1b, nW1,
        (const float4*)W2, (ushort4*)W2b, nW2);

    hist_rank_kernel<<<(NNZ + tb - 1) / tb, tb, 0, stream>>>(e_idx, v_idx, cnt_e, cnt_v,
                                                             rank_e, rank_v, NNZ);

    // parallel 3-phase scans (multi-block — Round-5's single-block scan was a 10x regression)
    int nbE = (M + SCAN_B - 1) / SCAN_B;
    scan_block_kernel<<<nbE, SCAN_B, 0, stream>>>(cnt_e, e_off, bsums, M);
    scan_top_kernel<<<1, 64, 0, stream>>>(bsums, nbE);
    scan_add_kernel<<<nbE, SCAN_B, 0, stream>>>(e_off, bsums, M);

    int nbV = (N + SCAN_B - 1) / SCAN_B;
    scan_block_kernel<<<nbV, SCAN_B, 0, stream>>>(cnt_v, v_off, bsums, N);
    scan_top_kernel<<<1, 64, 0, stream>>>(bsums, nbV);
    scan_add_kernel<<<nbV, SCAN_B, 0, stream>>>(v_off, bsums, N);

    set_tail_kernel<<<1, 64, 0, stream>>>(e_off, v_off, NNZ, M, N);

    scatter_kernel<<<(NNZ + tb - 1) / tb, tb, 0, stream>>>(e_idx, v_idx, e_off, v_off,
                                                           rank_e, rank_v, e_lst, v_lst, NNZ);

    // ---- conv1 ----
    seg_mean_w4<<<((size_t)M * 64 + tb - 1) / tb, tb, 0, stream>>>(
        (const ushort4*)Xb, (ushort4*)Aggb, e_off, e_lst, M, 0);
    gemm_mfma_bf16<<<dim3(H_DIM / 64, (M + 63) / 64), 256, 0, stream>>>(Aggb, W1b, b1, Yb, M, IN_DIM, H_DIM);
    seg_mean_w4<<<((size_t)N * 64 + tb - 1) / tb, tb, 0, stream>>>(
        (const ushort4*)Yb, (ushort4*)h1b, v_off, v_lst, N, 1);

    // ---- conv2 ----
    seg_mean_w4<<<((size_t)M * 64 + tb - 1) / tb, tb, 0, stream>>>(
        (const ushort4*)h1b, (ushort4*)Aggb, e_off, e_lst, M, 0);
    gemm_mfma_bf16<<<dim3(OUT_DIM / 64, (M + 63) / 64), 256, 0, stream>>>(Aggb, W2b, b2, Yb, M, H_DIM, OUT_DIM);
    seg_mean_w2<<<((size_t)N * 64 + tb - 1) / tb, tb, 0, stream>>>(
        (const ushort2*)Yb, (ushort2*)Xb, v_off, v_lst, N, 1);

    // ---- link head ----
    link_head<<<((size_t)L * 64 + tb - 1) / tb, tb, 0, stream>>>(
        (const ushort2*)Xb, link, fcw, fcb, out, L);
}